// Round 2
// baseline (2977.242 us; speedup 1.0000x reference)
//
#include <hip/hip_runtime.h>
#include <hip/hip_bf16.h>

#define UNIT 20
#define HID 36
#define G4 144      // 4*HID
#define INW 80      // 4*UNIT
#define NCLS 3
#define TT 40960
#define SS 2048     // TT/UNIT
#define CH 16       // timesteps per chunk
#define NCH (SS/CH) // 128 chunks

__device__ __forceinline__ float exp2_hw(float x){ float r; asm("v_exp_f32 %0, %1" : "=v"(r) : "v"(x)); return r; }
__device__ __forceinline__ float rcp_hw(float x){ float r; asm("v_rcp_f32 %0, %1" : "=v"(r) : "v"(x)); return r; }
__device__ __forceinline__ float sigm_hw(float x){ return rcp_hw(1.f + exp2_hw(-1.4426950408889634f * x)); }
__device__ __forceinline__ float tanh_hw(float x){ return 1.f - 2.f * rcp_hw(1.f + exp2_hw(2.8853900817779268f * x)); }
__device__ __forceinline__ float rl(float v, int l){
    return __uint_as_float(__builtin_amdgcn_readlane(__float_as_uint(v), l));
}

__global__ __launch_bounds__(256)
void lstm_fused(const float* __restrict__ x, const float* __restrict__ h0,
                const float* __restrict__ c0, const float* __restrict__ W_ih,
                const float* __restrict__ W_hh, const float* __restrict__ b_ih,
                const float* __restrict__ b_hh, const float* __restrict__ fc1_w,
                const float* __restrict__ fc1_b, const float* __restrict__ fc2_w,
                const float* __restrict__ fc2_b, float* __restrict__ out)
{
    const int b    = blockIdx.x;
    const int tid  = threadIdx.x;
    const int wid  = tid >> 6;
    const int lane = tid & 63;
    const int cwave = b & 3;                 // decorrelate consumer SIMD across blocks
    const bool cons = (wid == cwave);
    const int pid  = ((wid < cwave) ? wid : wid - 1) * 64 + lane;   // 0..191 producer id

    __shared__ __align__(16) float xin[2][CH][INW];   // 10 KB
    __shared__ __align__(16) float xw[2][CH][G4];     // 18 KB
    __shared__ __align__(16) float h_fin[HID];
    __shared__ __align__(16) float fc1_s[16];

    // producer: W_ih row (80 used). consumer: 4 W_hh rows (144). Shared storage.
    float wreg[G4];
    float bias = 0.f;
    float hval = 0.f, cval = 0.f;
    float hs[HID];                            // uniform (SGPR) after readlane

    const int jj = (lane < HID) ? lane : 0;   // clamp: lanes 36-63 duplicate lane 0

    if (cons) {
        #pragma unroll
        for (int g = 0; g < 4; ++g) {
            const float4* wr = (const float4*)(W_hh + (size_t)(g * HID + jj) * HID); // 144B rows, 16B aligned
            #pragma unroll
            for (int q = 0; q < HID/4; ++q) {
                float4 v = wr[q];
                wreg[g*HID + 4*q+0] = v.x; wreg[g*HID + 4*q+1] = v.y;
                wreg[g*HID + 4*q+2] = v.z; wreg[g*HID + 4*q+3] = v.w;
            }
        }
        hval = h0[b*HID + jj];
        cval = c0[b*HID + jj];
        #pragma unroll
        for (int q = 0; q < HID; ++q) hs[q] = rl(hval, q);
    } else {
        const int r = (pid < G4) ? pid : 0;
        const float4* wr = (const float4*)(W_ih + (size_t)r * INW);  // 320B rows
        #pragma unroll
        for (int q = 0; q < INW/4; ++q) {
            float4 v = wr[q];
            wreg[4*q+0] = v.x; wreg[4*q+1] = v.y; wreg[4*q+2] = v.z; wreg[4*q+3] = v.w;
        }
        bias = b_ih[r] + b_hh[r];
    }

    const float* xb = x + (size_t)b * 4 * TT;

    // prologue: stage chunk 0 into xin[0]
    if (!cons) {
        for (int j = pid; j < 4*CH*UNIT; j += 192) {
            int c  = j / (CH*UNIT);
            int rr = j - c * (CH*UNIT);          // s*UNIT + u
            xin[0][rr / UNIT][c*UNIT + (rr % UNIT)] = xb[c*TT + rr];
        }
    }
    __syncthreads();

    for (int k = 0; k <= NCH; ++k) {
        if (!cons) {
            if (k < NCH) {
                // stage chunk k+1 into xin[(k+1)&1]
                if (k + 1 < NCH) {
                    const int base = (k+1) * CH * UNIT;
                    float* xd = &xin[(k+1)&1][0][0];
                    for (int j = pid; j < 4*CH*UNIT; j += 192) {
                        int c  = j / (CH*UNIT);
                        int rr = j - c * (CH*UNIT);
                        xd[(rr / UNIT) * INW + c*UNIT + (rr % UNIT)] = xb[c*TT + base + rr];
                    }
                }
                // project chunk k from xin[k&1] into xw[k&1]
                if (pid < G4) {
                    const int cb = k & 1;
                    for (int s = 0; s < CH; ++s) {
                        const float4* xv = (const float4*)xin[cb][s];
                        float a0 = bias, a1 = 0.f, a2 = 0.f, a3 = 0.f;
                        #pragma unroll
                        for (int q = 0; q < INW/4; ++q) {
                            float4 v = xv[q];
                            a0 += v.x * wreg[4*q+0];
                            a1 += v.y * wreg[4*q+1];
                            a2 += v.z * wreg[4*q+2];
                            a3 += v.w * wreg[4*q+3];
                        }
                        xw[cb][s][pid] = (a0 + a1) + (a2 + a3);
                    }
                }
            }
        } else {
            if (k > 0) {
                const int cb = (k-1) & 1;
                for (int s = 0; s < CH; ++s) {
                    float ai = xw[cb][s][jj];
                    float af = xw[cb][s][HID   + jj];
                    float ag = xw[cb][s][2*HID + jj];
                    float ao = xw[cb][s][3*HID + jj];
                    #pragma unroll
                    for (int q = 0; q < HID; ++q) {
                        ai += hs[q] * wreg[q];
                        af += hs[q] * wreg[HID   + q];
                        ag += hs[q] * wreg[2*HID + q];
                        ao += hs[q] * wreg[3*HID + q];
                    }
                    float gi = sigm_hw(ai);
                    float gf = sigm_hw(af);
                    float gg = tanh_hw(ag);
                    float go = sigm_hw(ao);
                    cval = gf * cval + gi * gg;
                    hval = go * tanh_hw(cval);
                    #pragma unroll
                    for (int q = 0; q < HID; ++q) hs[q] = rl(hval, q);
                }
            }
        }
        __syncthreads();
    }

    if (cons && lane < HID) h_fin[lane] = hval;
    __syncthreads();

    if (tid < 16) {
        float a = fc1_b[tid];
        #pragma unroll
        for (int j = 0; j < HID; ++j) a += h_fin[j] * fc1_w[tid*HID + j];
        fc1_s[tid] = fmaxf(a, 0.f);
    }
    __syncthreads();
    if (tid < NCLS) {
        float a = fc2_b[tid];
        #pragma unroll
        for (int j = 0; j < 16; ++j) a += fc1_s[j] * fc2_w[tid*16 + j];
        out[b*NCLS + tid] = a;
    }
}

extern "C" void kernel_launch(void* const* d_in, const int* in_sizes, int n_in,
                              void* d_out, int out_size, void* d_ws, size_t ws_size,
                              hipStream_t stream) {
    const float* x     = (const float*)d_in[0];
    const float* h0    = (const float*)d_in[1];
    const float* c0    = (const float*)d_in[2];
    const float* W_ih  = (const float*)d_in[3];
    const float* W_hh  = (const float*)d_in[4];
    const float* b_ih  = (const float*)d_in[5];
    const float* b_hh  = (const float*)d_in[6];
    const float* fc1_w = (const float*)d_in[7];
    const float* fc1_b = (const float*)d_in[8];
    const float* fc2_w = (const float*)d_in[9];
    const float* fc2_b = (const float*)d_in[10];
    float* out = (float*)d_out;

    lstm_fused<<<512, 256, 0, stream>>>(x, h0, c0, W_ih, W_hh, b_ih, b_hh,
                                        fc1_w, fc1_b, fc2_w, fc2_b, out);
}

// Round 3
// 2071.563 us; speedup vs baseline: 1.4372x; 1.4372x over previous
//
#include <hip/hip_runtime.h>
#include <hip/hip_bf16.h>

#define UNIT 20
#define HID 36
#define G4 144      // 4*HID
#define INW 80      // 4*UNIT
#define NCLS 3
#define TT 40960
#define SS 2048     // TT/UNIT
#define BB 512

__device__ __forceinline__ float exp2_hw(float x){ float r; asm("v_exp_f32 %0, %1" : "=v"(r) : "v"(x)); return r; }
__device__ __forceinline__ float rcp_hw(float x){ float r; asm("v_rcp_f32 %0, %1" : "=v"(r) : "v"(x)); return r; }
__device__ __forceinline__ float sigm_hw(float x){ return rcp_hw(1.f + exp2_hw(-1.4426950408889634f * x)); }
__device__ __forceinline__ float tanh_hw(float x){ return 1.f - 2.f * rcp_hw(1.f + exp2_hw(2.8853900817779268f * x)); }
__device__ __forceinline__ float rl(float v, int l){
    return __uint_as_float(__builtin_amdgcn_readlane(__float_as_uint(v), l));
}

// ---------------- kernel 1: input projection xW -> workspace ----------------
// grid = BB * nseq blocks, 192 threads. Block (b, r) covers local steps
// [r*128, r*128+mysteps) of the current chunk. Writes xw[ls][b][144] fp32.
__global__ __launch_bounds__(192)
void lstm_proj(const float* __restrict__ x, const float* __restrict__ W_ih,
               const float* __restrict__ b_ih, const float* __restrict__ b_hh,
               float* __restrict__ xw, int s0, int cnt, int nseq)
{
    const int bid = blockIdx.x;
    const int r   = bid % nseq;
    const int b   = bid / nseq;
    const int tid = threadIdx.x;
    const int base_local = r * 128;
    const int mysteps = min(128, cnt - base_local);

    __shared__ __align__(16) float xin[16][INW];

    float wih[INW]; float bias = 0.f;
    if (tid < G4) {
        const float4* wr = (const float4*)(W_ih + (size_t)tid * INW);
        #pragma unroll
        for (int q = 0; q < INW/4; ++q) {
            float4 v = wr[q];
            wih[4*q+0]=v.x; wih[4*q+1]=v.y; wih[4*q+2]=v.z; wih[4*q+3]=v.w;
        }
        bias = b_ih[tid] + b_hh[tid];
    }
    const float* xb = x + (size_t)b * 4 * TT;

    for (int sub = 0; sub < mysteps; sub += 16) {
        const int sg = s0 + base_local + sub;        // absolute step of this 16-block
        __syncthreads();                             // xin safe to overwrite
        // stage 16 steps: 4 channels x 320 floats = 320 float4 (4|20 -> never crosses a step)
        for (int j = tid; j < 320; j += 192) {
            int c = j / 80, q = j - c*80;
            float4 v = ((const float4*)(xb + (size_t)c*TT + (size_t)sg*UNIT))[q];
            int e = q*4; int sl = e / UNIT, u = e - sl*UNIT;
            *(float4*)&xin[sl][c*UNIT + u] = v;
        }
        __syncthreads();
        if (tid < G4) {
            for (int s = 0; s < 16; ++s) {
                const float4* xv = (const float4*)xin[s];
                float a0 = bias, a1 = 0.f, a2 = 0.f, a3 = 0.f;
                #pragma unroll
                for (int q = 0; q < INW/4; ++q) {
                    float4 v = xv[q];
                    a0 += v.x * wih[4*q+0];
                    a1 += v.y * wih[4*q+1];
                    a2 += v.z * wih[4*q+2];
                    a3 += v.w * wih[4*q+3];
                }
                xw[((size_t)(base_local + sub + s) * BB + b) * G4 + tid] = (a0+a1)+(a2+a3);
            }
        }
    }
}

// ---------------- kernel 2: barrier-free recurrence ----------------
// grid = 128 blocks x 256 threads; wave w owns batch blockIdx.x*4+w.
// Lane j<36 owns hidden unit j: 4 W_hh rows in VGPRs, h broadcast via readlane->SGPR.
__global__ __launch_bounds__(256)
void lstm_recur(const float* __restrict__ xw, const float* __restrict__ h0,
                const float* __restrict__ c0, const float* __restrict__ W_hh,
                const float* __restrict__ fc1_w, const float* __restrict__ fc1_b,
                const float* __restrict__ fc2_w, const float* __restrict__ fc2_b,
                float* __restrict__ state, float* __restrict__ out, int s0, int cnt)
{
    const int wid  = threadIdx.x >> 6;
    const int lane = threadIdx.x & 63;
    const int b    = blockIdx.x * 4 + wid;
    const int jj   = (lane < HID) ? lane : 0;

    float wreg[G4];
    #pragma unroll
    for (int g = 0; g < 4; ++g) {
        const float* wr = W_hh + (size_t)(g*HID + jj) * HID;
        #pragma unroll
        for (int q = 0; q < HID; ++q) wreg[g*HID + q] = wr[q];
    }

    float hval, cval;
    if (s0 == 0) { hval = h0[b*HID + jj];    cval = c0[b*HID + jj]; }
    else         { hval = state[b*HID + jj]; cval = state[BB*HID + b*HID + jj]; }

    float hs[HID];
    #pragma unroll
    for (int q = 0; q < HID; ++q) hs[q] = rl(hval, q);

    const float*  xp     = xw + (size_t)b * G4 + jj;
    const size_t  STRIDE = (size_t)BB * G4;

    float qa[8][4], qb[8][4];

#define LOADBANK(dst, base) { \
    _Pragma("unroll") for (int u = 0; u < 8; ++u) { \
        int ss = (base) + u; \
        const float* p = xp + (size_t)((ss < cnt) ? ss : 0) * STRIDE; \
        _Pragma("unroll") for (int g = 0; g < 4; ++g) dst[u][g] = p[g*HID]; \
    } }

#define DOSTEP(bk, u) { \
    float ai = bk[u][0], af = bk[u][1], ag = bk[u][2], ao = bk[u][3]; \
    _Pragma("unroll") for (int q = 0; q < HID; ++q) { \
        ai += hs[q] * wreg[q]; \
        af += hs[q] * wreg[HID   + q]; \
        ag += hs[q] * wreg[2*HID + q]; \
        ao += hs[q] * wreg[3*HID + q]; \
    } \
    float gi = sigm_hw(ai), gf = sigm_hw(af), gg = tanh_hw(ag), go = sigm_hw(ao); \
    cval = gf * cval + gi * gg; \
    hval = go * tanh_hw(cval); \
    _Pragma("unroll") for (int q = 0; q < HID; ++q) hs[q] = rl(hval, q); }

    LOADBANK(qa, 0);
    for (int s8 = 0; s8 < cnt; s8 += 16) {
        LOADBANK(qb, s8 + 8);
        DOSTEP(qa,0) DOSTEP(qa,1) DOSTEP(qa,2) DOSTEP(qa,3)
        DOSTEP(qa,4) DOSTEP(qa,5) DOSTEP(qa,6) DOSTEP(qa,7)
        LOADBANK(qa, s8 + 16);
        DOSTEP(qb,0) DOSTEP(qb,1) DOSTEP(qb,2) DOSTEP(qb,3)
        DOSTEP(qb,4) DOSTEP(qb,5) DOSTEP(qb,6) DOSTEP(qb,7)
    }
#undef LOADBANK
#undef DOSTEP

    if (s0 + cnt == SS) {
        // classifier head, in-wave
        float a1 = 0.f;
        if (lane < 16) {
            a1 = fc1_b[lane];
            #pragma unroll
            for (int k = 0; k < HID; ++k) a1 += hs[k] * fc1_w[lane*HID + k];
            a1 = fmaxf(a1, 0.f);
        }
        float f1[16];
        #pragma unroll
        for (int k = 0; k < 16; ++k) f1[k] = rl(a1, k);
        if (lane < NCLS) {
            float a2 = fc2_b[lane];
            #pragma unroll
            for (int k = 0; k < 16; ++k) a2 += f1[k] * fc2_w[lane*16 + k];
            out[b*NCLS + lane] = a2;
        }
    } else {
        if (lane < HID) {
            state[b*HID + lane]          = hval;
            state[BB*HID + b*HID + lane] = cval;
        }
    }
}

// ---------------- fallback (R1 fused kernel) for undersized workspace ----------------
__global__ __launch_bounds__(192)
void lstm_fused(const float* __restrict__ x, const float* __restrict__ h0,
                const float* __restrict__ c0, const float* __restrict__ W_ih,
                const float* __restrict__ W_hh, const float* __restrict__ b_ih,
                const float* __restrict__ b_hh, const float* __restrict__ fc1_w,
                const float* __restrict__ fc1_b, const float* __restrict__ fc2_w,
                const float* __restrict__ fc2_b, float* __restrict__ out)
{
    const int b = blockIdx.x;
    const int t = threadIdx.x;
    __shared__ __align__(16) float xin[16][INW];
    __shared__ __align__(16) float xwl[16][G4];
    __shared__ __align__(16) float h_s[HID];
    __shared__ __align__(16) float g_s[G4];
    float wih[INW]; float whh[HID];
    float bias = 0.f, K = 0.f, Aa = 0.f, Bb = 0.f;
    if (t < G4) {
        const float4* wr = (const float4*)(W_ih + t * INW);
        #pragma unroll
        for (int i = 0; i < INW/4; ++i) { float4 v = wr[i]; wih[4*i]=v.x; wih[4*i+1]=v.y; wih[4*i+2]=v.z; wih[4*i+3]=v.w; }
        const float4* hr = (const float4*)(W_hh + t * HID);
        #pragma unroll
        for (int j = 0; j < HID/4; ++j) { float4 v = hr[j]; whh[4*j]=v.x; whh[4*j+1]=v.y; whh[4*j+2]=v.z; whh[4*j+3]=v.w; }
        bias = b_ih[t] + b_hh[t];
        const bool tnh = (t >= 2*HID && t < 3*HID);
        K  = tnh ?  2.8853900817779268f : -1.4426950408889634f;
        Aa = tnh ?  1.f : 0.f;
        Bb = tnh ? -2.f : 1.f;
    }
    float c = 0.f;
    if (t < HID) { c = c0[b*HID + t]; h_s[t] = h0[b*HID + t]; }
    __syncthreads();
    const float* xb = x + (size_t)b * 4 * TT;
    for (int ck = 0; ck < SS/16; ++ck) {
        const int base = ck * 16 * UNIT;
        for (int j = t; j < 4*16*UNIT; j += 192) {
            int chn = j / (16*UNIT); int r = j - chn*(16*UNIT);
            xin[r/UNIT][chn*UNIT + (r%UNIT)] = xb[chn*TT + base + r];
        }
        __syncthreads();
        if (t < G4) {
            for (int s = 0; s < 16; ++s) {
                const float4* xv = (const float4*)xin[s];
                float a0 = bias, a1 = 0.f, a2 = 0.f, a3 = 0.f;
                #pragma unroll
                for (int i = 0; i < INW/4; ++i) {
                    float4 v = xv[i];
                    a0 += v.x*wih[4*i]; a1 += v.y*wih[4*i+1]; a2 += v.z*wih[4*i+2]; a3 += v.w*wih[4*i+3];
                }
                xwl[s][t] = (a0+a1)+(a2+a3);
            }
        }
        __syncthreads();
        for (int s = 0; s < 16; ++s) {
            if (t < G4) {
                const float4* hv = (const float4*)h_s;
                float a0 = xwl[s][t], a1 = 0.f, a2 = 0.f, a3 = 0.f;
                #pragma unroll
                for (int j = 0; j < HID/4; ++j) {
                    float4 v = hv[j];
                    a0 += v.x*whh[4*j]; a1 += v.y*whh[4*j+1]; a2 += v.z*whh[4*j+2]; a3 += v.w*whh[4*j+3];
                }
                float acc = (a0+a1)+(a2+a3);
                g_s[t] = Aa + Bb * rcp_hw(1.f + exp2_hw(K * acc));
            }
            __syncthreads();
            if (t < HID) {
                float ig=g_s[t], fg=g_s[HID+t], gg=g_s[2*HID+t], og=g_s[3*HID+t];
                c = fg*c + ig*gg;
                h_s[t] = og * tanh_hw(c);
            }
            __syncthreads();
        }
    }
    if (t < 16) {
        float a = fc1_b[t];
        #pragma unroll
        for (int j = 0; j < HID; ++j) a += h_s[j]*fc1_w[t*HID+j];
        g_s[t] = fmaxf(a, 0.f);
    }
    __syncthreads();
    if (t < NCLS) {
        float a = fc2_b[t];
        #pragma unroll
        for (int j = 0; j < 16; ++j) a += g_s[j]*fc2_w[t*16+j];
        out[b*NCLS + t] = a;
    }
}

extern "C" void kernel_launch(void* const* d_in, const int* in_sizes, int n_in,
                              void* d_out, int out_size, void* d_ws, size_t ws_size,
                              hipStream_t stream) {
    const float* x     = (const float*)d_in[0];
    const float* h0    = (const float*)d_in[1];
    const float* c0    = (const float*)d_in[2];
    const float* W_ih  = (const float*)d_in[3];
    const float* W_hh  = (const float*)d_in[4];
    const float* b_ih  = (const float*)d_in[5];
    const float* b_hh  = (const float*)d_in[6];
    const float* fc1_w = (const float*)d_in[7];
    const float* fc1_b = (const float*)d_in[8];
    const float* fc2_w = (const float*)d_in[9];
    const float* fc2_b = (const float*)d_in[10];
    float* out = (float*)d_out;

    // workspace layout: [h state 512*36][c state 512*36][xw chunk buffer]
    const size_t state_floats = (size_t)BB * HID * 2;
    long cap = (long)(ws_size / 4) - (long)state_floats;
    long sc  = (cap > 0) ? cap / ((long)BB * G4) : 0;
    int  SC  = (int)((sc > SS) ? SS : sc) & ~15;

    if (SC < 16) {
        // workspace too small — proven fused fallback
        lstm_fused<<<BB, 192, 0, stream>>>(x, h0, c0, W_ih, W_hh, b_ih, b_hh,
                                           fc1_w, fc1_b, fc2_w, fc2_b, out);
        return;
    }

    float* state = (float*)d_ws;
    float* xwbuf = state + state_floats;

    for (int s0 = 0; s0 < SS; s0 += SC) {
        int cnt = SS - s0; if (cnt > SC) cnt = SC;
        int nseq = (cnt + 127) / 128;
        lstm_proj<<<BB * nseq, 192, 0, stream>>>(x, W_ih, b_ih, b_hh, xwbuf, s0, cnt, nseq);
        lstm_recur<<<BB / 4, 256, 0, stream>>>(xwbuf, h0, c0, W_hh,
                                               fc1_w, fc1_b, fc2_w, fc2_b,
                                               state, out, s0, cnt);
    }
}